// Round 1
// baseline (212.793 us; speedup 1.0000x reference)
//
#include <hip/hip_runtime.h>
#include <math.h>

// Problem: output [B=2, C=8, H=128, W=128, D=128] fp32.
// t = (x > 0.5 ? x : 0); per (b,c): s = sum t, sy = sum t*(y/H), sx = sum t*(x/W),
// sz = sum t*(z/D); centroids = weighted/ s; 8 relations -> scalar loss.
// Memory-bound: 134 MB read, target ~21 us @ 6.3 TB/s.

#define SLICES 16            // B*C
#define SLICE_ELEMS (128*128*128)
#define BLOCKS_PER_SLICE 64
#define THREADS 256

__global__ void gsl_init_ws(float* __restrict__ ws) {
    int i = threadIdx.x;
    if (i < SLICES * 4) ws[i] = 0.0f;
}

__global__ __launch_bounds__(THREADS)
void gsl_reduce(const float* __restrict__ in, float* __restrict__ ws) {
    const int slice = blockIdx.y;
    const float4* p = reinterpret_cast<const float4*>(in + (size_t)slice * SLICE_ELEMS);
    const int tid = threadIdx.x;
    const int nvec = SLICE_ELEMS / 4;           // 524288
    const int stride = BLOCKS_PER_SLICE * THREADS;  // 16384 -> 32 iters/thread

    float s = 0.0f, sy = 0.0f, sx = 0.0f, sz = 0.0f;

    for (int v = blockIdx.x * THREADS + tid; v < nvec; v += stride) {
        float4 f = p[v];
        int e = v << 2;                          // element index of f.x
        float t0 = f.x > 0.5f ? f.x : 0.0f;
        float t1 = f.y > 0.5f ? f.y : 0.0f;
        float t2 = f.z > 0.5f ? f.z : 0.0f;
        float t3 = f.w > 0.5f ? f.w : 0.0f;
        float ts = (t0 + t1) + (t2 + t3);
        float zz = (float)(e & 127);             // z of f.x (z varies fastest)
        float xx = (float)((e >> 7) & 127);
        float yy = (float)(e >> 14);
        s  += ts;
        sy += ts * yy;
        sx += ts * xx;
        sz += ts * zz + (t1 + 2.0f * t2 + 3.0f * t3);
    }

    // normalize coords by 1/128 once (H=W=D=128)
    const float inv = 1.0f / 128.0f;
    sy *= inv; sx *= inv; sz *= inv;

    // wave64 shuffle reduction
    #pragma unroll
    for (int off = 32; off > 0; off >>= 1) {
        s  += __shfl_down(s,  off, 64);
        sy += __shfl_down(sy, off, 64);
        sx += __shfl_down(sx, off, 64);
        sz += __shfl_down(sz, off, 64);
    }

    __shared__ float sh[4][4];                   // 4 waves x {s,sy,sx,sz}
    const int wave = tid >> 6;
    const int lane = tid & 63;
    if (lane == 0) {
        sh[wave][0] = s; sh[wave][1] = sy; sh[wave][2] = sx; sh[wave][3] = sz;
    }
    __syncthreads();
    if (tid == 0) {
        float a = 0.0f, b = 0.0f, c = 0.0f, d = 0.0f;
        #pragma unroll
        for (int w = 0; w < 4; ++w) {
            a += sh[w][0]; b += sh[w][1]; c += sh[w][2]; d += sh[w][3];
        }
        atomicAdd(&ws[slice * 4 + 0], a);
        atomicAdd(&ws[slice * 4 + 1], b);
        atomicAdd(&ws[slice * 4 + 2], c);
        atomicAdd(&ws[slice * 4 + 3], d);
    }
}

__global__ void gsl_finalize(const float* __restrict__ ws, float* __restrict__ out) {
    if (threadIdx.x != 0 || blockIdx.x != 0) return;

    float cy[SLICES], cx[SLICES], cz[SLICES];
    for (int i = 0; i < SLICES; ++i) {
        float s = ws[i * 4 + 0];
        cy[i] = ws[i * 4 + 1] / s;
        cx[i] = ws[i * 4 + 2] / s;
        cz[i] = ws[i * 4 + 3] / s;
    }

    const int   ri[8] = {0, 1, 2, 3, 4, 5, 6, 0};
    const int   rj[8] = {1, 2, 3, 4, 5, 6, 7, 7};
    const float gy[8] = { 0.1f, 0.0f, -0.1f, 0.0f,  0.05f, 0.0f, 0.1f, -0.05f};
    const float gx[8] = { 0.0f, 0.1f,  0.05f, 0.0f, -0.05f, 0.1f, 0.0f,  0.05f};
    const float gz[8] = { 0.05f, 0.0f, 0.0f,  0.1f,  0.0f, -0.1f, 0.0f,  0.05f};

    float loss = 0.0f;
    for (int r = 0; r < 8; ++r) {
        for (int b = 0; b < 2; ++b) {
            int i = b * 8 + ri[r];
            int j = b * 8 + rj[r];
            float dy = cy[i] - cy[j] - gy[r];
            float dx = cx[i] - cx[j] - gx[r];
            float dz = cz[i] - cz[j] - gz[r];
            if (!isfinite(dy)) dy = 0.0f;
            if (!isfinite(dx)) dx = 0.0f;
            if (!isfinite(dz)) dz = 0.0f;
            // mean over batch (B=2) of squared diffs, summed over relations & axes
            loss += 0.5f * (dy * dy + dx * dx + dz * dz);
        }
    }
    out[0] = loss;
}

extern "C" void kernel_launch(void* const* d_in, const int* in_sizes, int n_in,
                              void* d_out, int out_size, void* d_ws, size_t ws_size,
                              hipStream_t stream) {
    const float* in = (const float*)d_in[0];
    float* out = (float*)d_out;
    float* ws = (float*)d_ws;   // 64 floats: 16 slices x {s, sy, sx, sz}

    gsl_init_ws<<<1, 64, 0, stream>>>(ws);
    gsl_reduce<<<dim3(BLOCKS_PER_SLICE, SLICES), THREADS, 0, stream>>>(in, ws);
    gsl_finalize<<<1, 64, 0, stream>>>(ws, out);
}

// Round 2
// 192.501 us; speedup vs baseline: 1.1054x; 1.1054x over previous
//
#include <hip/hip_runtime.h>
#include <math.h>

// Problem: output [B=2, C=8, H=128, W=128, D=128] fp32.
// t = (x > 0.5 ? x : 0); per (b,c): s = sum t, sy = sum t*(y/H), sx = sum t*(x/W),
// sz = sum t*(z/D); centroids = weighted / s; 8 relations -> scalar loss.
// Memory-bound: 134 MB read -> ~21 us floor @ 6.3 TB/s.
//
// R2 changes vs R1:
//  - no init kernel / no atomics: each block writes its partial {s,sy,sx,sz}
//    as one float4 to ws (all 1024 slots written unconditionally every call)
//  - exact 32-trip loop, #pragma unroll 8 -> 8 float4 loads in flight/wave
//  - single 256-thread finalize reduces all 16x64 partials via width-16 shuffles

#define SLICES 16            // B*C
#define SLICE_ELEMS (128*128*128)
#define BLOCKS_PER_SLICE 64
#define THREADS 256
#define NVEC (SLICE_ELEMS / 4)                 // 524288 float4 per slice
#define STRIDE (BLOCKS_PER_SLICE * THREADS)    // 16384 -> exactly 32 iters/thread

__global__ __launch_bounds__(THREADS)
void gsl_reduce(const float* __restrict__ in, float4* __restrict__ ws4) {
    const int slice = blockIdx.y;
    const float4* p = reinterpret_cast<const float4*>(in + (size_t)slice * SLICE_ELEMS);
    const int tid = threadIdx.x;
    const int base = blockIdx.x * THREADS + tid;   // 0..16383

    float s = 0.0f, sy = 0.0f, sx = 0.0f, sz = 0.0f;

    #pragma unroll 8
    for (int i = 0; i < 32; ++i) {
        const int v = base + i * STRIDE;
        float4 f = p[v];
        const int e = v << 2;                      // element index of f.x
        float t0 = f.x > 0.5f ? f.x : 0.0f;
        float t1 = f.y > 0.5f ? f.y : 0.0f;
        float t2 = f.z > 0.5f ? f.z : 0.0f;
        float t3 = f.w > 0.5f ? f.w : 0.0f;
        float ts = (t0 + t1) + (t2 + t3);
        float zz = (float)(e & 127);               // z of f.x (z fastest)
        float xx = (float)((e >> 7) & 127);
        float yy = (float)(e >> 14);
        s  += ts;
        sy += ts * yy;
        sx += ts * xx;
        sz += ts * zz + (t1 + 2.0f * t2 + 3.0f * t3);
    }

    const float inv = 1.0f / 128.0f;               // normalize coords (H=W=D=128)
    sy *= inv; sx *= inv; sz *= inv;

    #pragma unroll
    for (int off = 32; off > 0; off >>= 1) {
        s  += __shfl_down(s,  off, 64);
        sy += __shfl_down(sy, off, 64);
        sx += __shfl_down(sx, off, 64);
        sz += __shfl_down(sz, off, 64);
    }

    __shared__ float4 sh[4];
    const int wave = tid >> 6;
    const int lane = tid & 63;
    if (lane == 0) sh[wave] = make_float4(s, sy, sx, sz);
    __syncthreads();
    if (tid == 0) {
        float4 a = sh[0], b = sh[1], c = sh[2], d = sh[3];
        float4 r = make_float4((a.x + b.x) + (c.x + d.x),
                               (a.y + b.y) + (c.y + d.y),
                               (a.z + b.z) + (c.z + d.z),
                               (a.w + b.w) + (c.w + d.w));
        ws4[slice * BLOCKS_PER_SLICE + blockIdx.x] = r;   // no atomics, no init
    }
}

__global__ __launch_bounds__(THREADS)
void gsl_finalize(const float4* __restrict__ ws4, float* __restrict__ out) {
    const int t = threadIdx.x;
    const int slice = t >> 4;   // 0..15 (16 lanes per slice, contiguous in wave)
    const int chunk = t & 15;   // 0..15, each covers 4 block-partials

    float s = 0.0f, sy = 0.0f, sx = 0.0f, sz = 0.0f;
    #pragma unroll
    for (int i = 0; i < 4; ++i) {
        float4 f = ws4[slice * BLOCKS_PER_SLICE + chunk * 4 + i];
        s += f.x; sy += f.y; sx += f.z; sz += f.w;
    }
    #pragma unroll
    for (int off = 8; off > 0; off >>= 1) {        // reduce within 16-lane group
        s  += __shfl_down(s,  off, 16);
        sy += __shfl_down(sy, off, 16);
        sx += __shfl_down(sx, off, 16);
        sz += __shfl_down(sz, off, 16);
    }

    __shared__ float cy[SLICES], cx[SLICES], cz[SLICES];
    if (chunk == 0) {
        cy[slice] = sy / s;
        cx[slice] = sx / s;
        cz[slice] = sz / s;
    }
    __syncthreads();

    if (t == 0) {
        const int   ri[8] = {0, 1, 2, 3, 4, 5, 6, 0};
        const int   rj[8] = {1, 2, 3, 4, 5, 6, 7, 7};
        const float gy[8] = { 0.1f, 0.0f, -0.1f, 0.0f,  0.05f, 0.0f, 0.1f, -0.05f};
        const float gx[8] = { 0.0f, 0.1f,  0.05f, 0.0f, -0.05f, 0.1f, 0.0f,  0.05f};
        const float gz[8] = { 0.05f, 0.0f, 0.0f,  0.1f,  0.0f, -0.1f, 0.0f,  0.05f};

        float loss = 0.0f;
        #pragma unroll
        for (int r = 0; r < 8; ++r) {
            #pragma unroll
            for (int b = 0; b < 2; ++b) {
                int i = b * 8 + ri[r];
                int j = b * 8 + rj[r];
                float dy = cy[i] - cy[j] - gy[r];
                float dx = cx[i] - cx[j] - gx[r];
                float dz = cz[i] - cz[j] - gz[r];
                if (!isfinite(dy)) dy = 0.0f;
                if (!isfinite(dx)) dx = 0.0f;
                if (!isfinite(dz)) dz = 0.0f;
                loss += 0.5f * (dy * dy + dx * dx + dz * dz);  // mean over B=2
            }
        }
        out[0] = loss;
    }
}

extern "C" void kernel_launch(void* const* d_in, const int* in_sizes, int n_in,
                              void* d_out, int out_size, void* d_ws, size_t ws_size,
                              hipStream_t stream) {
    const float* in = (const float*)d_in[0];
    float* out = (float*)d_out;
    float4* ws4 = (float4*)d_ws;   // 1024 float4 partials: [slice][block]

    gsl_reduce<<<dim3(BLOCKS_PER_SLICE, SLICES), THREADS, 0, stream>>>(in, ws4);
    gsl_finalize<<<1, THREADS, 0, stream>>>(ws4, out);
}